// Round 1
// baseline (633.954 us; speedup 1.0000x reference)
//
#include <hip/hip_runtime.h>
#include <hip/hip_bf16.h>
#include <math.h>

#define B 8
#define T_MEL 400
#define N_MEL 80
#define L_TXT 128
#define D_TXT 512
#define E 256
#define HID 256
#define EMB 128
#define N_SPK 100
#define HH 128

// ---- workspace layout (float element offsets) ----
#define OFF_W      0
#define OFF_C      256
#define OFF_WXT    272
#define OFF_WQT    (OFF_WXT + N_MEL*E)        // 20752
#define OFF_WIHT   (OFF_WQT + D_TXT*E)        // 151824
#define OFF_BSUM   (OFF_WIHT + 2*2*256*512)   // 676112
#define OFF_X1     (OFF_BSUM + 2048)          // 678160
#define OFF_Q1     (OFF_X1 + B*T_MEL*E)       // 1497360
#define OFF_G      OFF_X1                      // gates overlay x1+q1 (dead by then)
#define OFF_H0     (OFF_Q1 + B*L_TXT*E)       // 1759504
#define OFF_O1     (OFF_H0 + B*L_TXT*E)       // 2021648
#define OFF_O2     (OFF_O1 + B*L_TXT*HID)     // 2283792

__device__ __forceinline__ float fast_sigmoid(float x){ return 1.f/(1.f+__expf(-x)); }
__device__ __forceinline__ float fast_tanh(float x){ float e=__expf(2.f*x); return 1.f - 2.f/(e+1.f); }

// ---- prep: w = Wout^T v, c = bout.v ; transposes WxT, WqT, WihT ; bias sums ----
__global__ void k_prep(const float* __restrict__ Wout, const float* __restrict__ bout,
                       const float* __restrict__ v,    const float* __restrict__ Wx,
                       const float* __restrict__ Wq,   const float* __restrict__ wih,
                       const float* __restrict__ bih,  const float* __restrict__ bhh,
                       float* __restrict__ ws){
  int blk = blockIdx.x, tid = threadIdx.x;
  if (blk == 0){
    float acc = 0.f;
    for (int j=0;j<E;j++) acc += Wout[j*E + tid] * v[j];
    ws[OFF_W + tid] = acc;
    if (tid==0){ float c=0.f; for(int j=0;j<E;j++) c += bout[j]*v[j]; ws[OFF_C]=c; }
  } else if (blk <= N_MEL){
    int m = blk-1;
    ws[OFF_WXT + m*E + tid] = Wx[tid*N_MEL + m];
  } else if (blk <= N_MEL + D_TXT){
    int k = blk-1-N_MEL;
    ws[OFF_WQT + k*E + tid] = Wq[tid*D_TXT + k];
  } else if (blk <= N_MEL + D_TXT + 1024){
    int idx = blk-1-N_MEL-D_TXT;      // ld*256 + k
    int ld = idx >> 8, k = idx & 255;
    for (int g = tid; g < 512; g += 256)
      ws[OFF_WIHT + idx*512 + g] = wih[(ld*512+g)*256 + k];
  } else {
    for (int i = tid; i < 2048; i += 256)
      ws[OFF_BSUM + i] = bih[i] + bhh[i];
  }
}

// ---- x1[b,t,e] = sum_m x[b,m,t]*Wx[e,m] + bx[e] ; t-tile 4 ----
__global__ __launch_bounds__(256) void k_x1(const float* __restrict__ x,
                                            const float* __restrict__ bx,
                                            float* __restrict__ ws){
  int blk = blockIdx.x; int b = blk/100; int t0 = (blk%100)*4; int tid = threadIdx.x;
  __shared__ float sx[N_MEL][4];
  for (int i = tid; i < N_MEL*4; i += 256){
    int m = i>>2, ii = i&3;
    sx[m][ii] = x[(b*N_MEL+m)*T_MEL + t0 + ii];
  }
  __syncthreads();
  float bxe = bx[tid];
  float a0=bxe,a1=bxe,a2=bxe,a3=bxe;
  const float* wxt = ws + OFF_WXT;
  #pragma unroll 4
  for (int m=0;m<N_MEL;m++){
    float w = wxt[m*E + tid];
    a0 += sx[m][0]*w; a1 += sx[m][1]*w; a2 += sx[m][2]*w; a3 += sx[m][3]*w;
  }
  float* x1 = ws + OFF_X1 + (b*T_MEL + t0)*E + tid;
  x1[0]=a0; x1[E]=a1; x1[2*E]=a2; x1[3*E]=a3;
}

// ---- q1[b,l,e] = sum_d text[b,l,d]*Wq[e,d] + bq[e] ; l-tile 4 ----
__global__ __launch_bounds__(256) void k_q1(const float* __restrict__ text,
                                            const float* __restrict__ bq,
                                            float* __restrict__ ws){
  int blk = blockIdx.x; int b = blk/32; int l0 = (blk%32)*4; int tid = threadIdx.x;
  __shared__ float st[4][D_TXT];
  for (int i = tid; i < 4*D_TXT; i += 256){
    int li = i / D_TXT, k = i % D_TXT;
    st[li][k] = text[(b*L_TXT + l0 + li)*D_TXT + k];
  }
  __syncthreads();
  float bqe = bq[tid];
  float a0=bqe,a1=bqe,a2=bqe,a3=bqe;
  const float* wqt = ws + OFF_WQT;
  #pragma unroll 2
  for (int k=0;k<D_TXT;k++){
    float w = wqt[k*E + tid];
    a0 += st[0][k]*w; a1 += st[1][k]*w; a2 += st[2][k]*w; a3 += st[3][k]*w;
  }
  float* q1 = ws + OFF_Q1 + (b*L_TXT + l0)*E + tid;
  q1[0]=a0; q1[E]=a1; q1[2*E]=a2; q1[3*E]=a3;
}

// ---- scores + masked softmax + context + h0 ; one block per (b,l) ----
__global__ __launch_bounds__(256) void k_score(const int* __restrict__ mel_len,
                                               float* __restrict__ ws,
                                               float* __restrict__ d_out){
  int blk = blockIdx.x; int b = blk >> 7; int l = blk & 127;
  int tid = threadIdx.x; int lane = tid & 63; int wv = tid >> 6;
  __shared__ float sl[T_MEL];
  __shared__ float red[8];
  const float* x1 = ws + OFF_X1 + b*T_MEL*E;
  const float* q1 = ws + OFF_Q1 + (b*L_TXT+l)*E;
  float qv[4], wv4[4];
  #pragma unroll
  for (int j=0;j<4;j++){ qv[j] = q1[lane+64*j]; wv4[j] = ws[OFF_W + lane + 64*j]; }
  float cc = ws[OFF_C];
  int len = mel_len[b];
  for (int t = wv; t < T_MEL; t += 4){
    const float* xr = x1 + t*E;
    float s = 0.f;
    #pragma unroll
    for (int j=0;j<4;j++) s += wv4[j]*fast_tanh(xr[lane+64*j] + qv[j]);
    #pragma unroll
    for (int off=32; off>=1; off>>=1) s += __shfl_xor(s, off);
    if (lane==0) sl[t] = s + cc;
  }
  __syncthreads();
  float mx = -3.0e38f;
  for (int t = tid; t < T_MEL; t += 256) if (t < len) mx = fmaxf(mx, sl[t]);
  #pragma unroll
  for (int off=32; off>=1; off>>=1) mx = fmaxf(mx, __shfl_xor(mx, off));
  if (lane==0) red[wv] = mx;
  __syncthreads();
  mx = fmaxf(fmaxf(red[0],red[1]),fmaxf(red[2],red[3]));
  float se = 0.f;
  for (int t = tid; t < T_MEL; t += 256){
    float p = (t < len) ? __expf(sl[t]-mx) : 0.f;
    sl[t] = p; se += p;
  }
  #pragma unroll
  for (int off=32; off>=1; off>>=1) se += __shfl_xor(se, off);
  if (lane==0) red[4+wv] = se;
  __syncthreads();
  float rsum = 1.f/(red[4]+red[5]+red[6]+red[7]);
  float* sc_out = d_out + 1824 + (b*L_TXT + l)*T_MEL;
  for (int t = tid; t < T_MEL; t += 256){
    float p = sl[t]*rsum;
    sl[t] = p; sc_out[t] = p;
  }
  __syncthreads();
  float a = 0.f;
  int e = tid;
  #pragma unroll 4
  for (int t = 0; t < len; t++) a += sl[t]*x1[t*E + e];
  ws[OFF_H0 + (b*L_TXT+l)*E + e] = q1[e] + a;
}

// ---- gates_in[b,dir,t,g] = gathered_in[b,row(t),:] @ WihT + (bih+bhh) ; t-tile 8 ----
__global__ __launch_bounds__(512) void k_gates(const float* __restrict__ in,
                                               const int* __restrict__ txt_len,
                                               float* __restrict__ gates, int layer,
                                               float* __restrict__ ws){
  int idx = blockIdx.x; int tt = idx & 15; int dir = (idx>>4)&1; int b = idx>>5;
  int tid = threadIdx.x;
  __shared__ float si[8][HID];
  int len = txt_len[b];
  for (int i = tid; i < 8*HID; i += 512){
    int r = i >> 8, k = i & 255;
    int t = tt*8 + r;
    int row = dir ? max(0, len-1-t) : t;
    si[r][k] = in[(b*L_TXT + row)*HID + k];
  }
  __syncthreads();
  int ld = layer*2 + dir;
  int g = tid;
  float bsum = ws[OFF_BSUM + ld*512 + g];
  float acc[8];
  #pragma unroll
  for (int r=0;r<8;r++) acc[r] = bsum;
  const float* wt = ws + OFF_WIHT + ld*256*512;
  for (int k=0;k<HID;k++){
    float w = wt[k*512 + g];
    #pragma unroll
    for (int r=0;r<8;r++) acc[r] += si[r][k]*w;
  }
  float* go = gates + ((b*2+dir)*L_TXT + tt*8)*512 + g;
  #pragma unroll
  for (int r=0;r<8;r++) go[r*512] = acc[r];
}

// ---- recurrent scan ; one block per (b,dir) ; weights in VGPRs ----
__global__ __launch_bounds__(1024) void k_scan(const float* __restrict__ gates,
                                               const float* __restrict__ whh_all,
                                               const int* __restrict__ txt_len,
                                               float* __restrict__ out, int layer){
  int dir = blockIdx.x & 1; int b = blockIdx.x >> 1;
  int tid = threadIdx.x; int g = tid>>1; int half = tid&1;
  __shared__ __align__(16) float h_lds[HH];
  __shared__ float gact[512];
  const float* wrow = whh_all + ((layer*2+dir)*512 + g)*HH + half*64;
  float w[64];
  #pragma unroll
  for (int j=0;j<64;j++) w[j] = wrow[j];
  float c_reg = 0.f;
  if (tid < HH) h_lds[tid] = 0.f;
  int len = txt_len[b];
  const float* gin = gates + (b*2+dir)*L_TXT*512 + g;
  __syncthreads();
  for (int step=0; step<L_TXT; step++){
    float acc = (half==0) ? gin[step*512] : 0.f;
    const float4* h4 = ((const float4*)h_lds) + half*16;
    #pragma unroll
    for (int j=0;j<16;j++){
      float4 hv = h4[j];
      acc += w[4*j]*hv.x + w[4*j+1]*hv.y + w[4*j+2]*hv.z + w[4*j+3]*hv.w;
    }
    acc += __shfl_xor(acc, 1);
    if (half==0){
      int gt = g >> 7;
      gact[g] = (gt==2) ? fast_tanh(acc) : fast_sigmoid(acc);
    }
    __syncthreads();
    if (tid < HH){
      c_reg = gact[HH+tid]*c_reg + gact[tid]*gact[2*HH+tid];
      float h = gact[3*HH+tid]*fast_tanh(c_reg);
      h_lds[tid] = h;
      if (dir==0){
        out[(b*L_TXT + step)*HID + tid] = h;
      } else {
        if (step < len) out[(b*L_TXT + (len-1-step))*HID + HH + tid] = h;
        if (step == 0){
          for (int p=len; p<L_TXT; p++) out[(b*L_TXT+p)*HID + HH + tid] = h;
        }
      }
    }
    __syncthreads();
  }
}

// ---- masked mean pool + p1/tanh + normalize + p2 ----
__global__ __launch_bounds__(256) void k_final(const float* __restrict__ o2,
                                               const int* __restrict__ txt_len,
                                               const float* __restrict__ p1w,
                                               const float* __restrict__ p1b,
                                               const float* __restrict__ p2w,
                                               const float* __restrict__ p2b,
                                               float* __restrict__ d_out){
  int b = blockIdx.x; int tid = threadIdx.x;
  __shared__ float pl[HID];
  __shared__ float ol[EMB];
  __shared__ float nrm;
  int len = txt_len[b];
  float s = 0.f;
  for (int t=0; t<len; t++) s += o2[(b*L_TXT+t)*HID + tid];
  pl[tid] = s / (float)len;
  __syncthreads();
  if (tid < EMB){
    float a = p1b[tid];
    for (int k=0;k<HID;k++) a += pl[k]*p1w[tid*HID+k];
    ol[tid] = fast_tanh(a);
  }
  __syncthreads();
  if (tid == 0){
    float q = 0.f;
    for (int k=0;k<EMB;k++) q += ol[k]*ol[k];
    nrm = rsqrtf(q);
  }
  __syncthreads();
  if (tid < EMB) d_out[800 + b*EMB + tid] = ol[tid]*nrm;
  if (tid < N_SPK){
    float a = p2b[tid];
    for (int k=0;k<EMB;k++) a += ol[k]*p2w[tid*EMB+k];
    d_out[b*N_SPK + tid] = a;
  }
}

extern "C" void kernel_launch(void* const* d_in, const int* in_sizes, int n_in,
                              void* d_out, int out_size, void* d_ws, size_t ws_size,
                              hipStream_t stream) {
  const float* x       = (const float*)d_in[0];
  const int*   mel_len = (const int*)  d_in[1];
  const float* text    = (const float*)d_in[2];
  const int*   txt_len = (const int*)  d_in[3];
  const float* Wx      = (const float*)d_in[4];
  const float* bx      = (const float*)d_in[5];
  const float* Wq      = (const float*)d_in[6];
  const float* bq      = (const float*)d_in[7];
  const float* Wout    = (const float*)d_in[8];
  const float* bout    = (const float*)d_in[9];
  const float* v       = (const float*)d_in[10];
  const float* wih     = (const float*)d_in[11];
  const float* whh     = (const float*)d_in[12];
  const float* bih     = (const float*)d_in[13];
  const float* bhh     = (const float*)d_in[14];
  const float* p1w     = (const float*)d_in[15];
  const float* p1b     = (const float*)d_in[16];
  const float* p2w     = (const float*)d_in[17];
  const float* p2b     = (const float*)d_in[18];
  float* ws  = (float*)d_ws;
  float* out = (float*)d_out;

  k_prep<<<1618, 256, 0, stream>>>(Wout, bout, v, Wx, Wq, wih, bih, bhh, ws);
  k_x1  <<<800, 256, 0, stream>>>(x, bx, ws);
  k_q1  <<<256, 256, 0, stream>>>(text, bq, ws);
  k_score<<<1024, 256, 0, stream>>>(mel_len, ws, out);

  float* G = ws + OFF_G;
  k_gates<<<256, 512, 0, stream>>>(ws + OFF_H0, txt_len, G, 0, ws);
  k_scan <<<16, 1024, 0, stream>>>(G, whh, txt_len, ws + OFF_O1, 0);
  k_gates<<<256, 512, 0, stream>>>(ws + OFF_O1, txt_len, G, 1, ws);
  k_scan <<<16, 1024, 0, stream>>>(G, whh, txt_len, ws + OFF_O2, 1);

  k_final<<<8, 256, 0, stream>>>(ws + OFF_O2, txt_len, p1w, p1b, p2w, p2b, out);
}

// Round 2
// 621.183 us; speedup vs baseline: 1.0206x; 1.0206x over previous
//
#include <hip/hip_runtime.h>
#include <hip/hip_bf16.h>
#include <math.h>

#define B 8
#define T_MEL 400
#define N_MEL 80
#define L_TXT 128
#define D_TXT 512
#define E 256
#define HID 256
#define EMB 128
#define N_SPK 100
#define HH 128

// ---- workspace layout (float element offsets) ----
#define OFF_W      0
#define OFF_C      256
#define OFF_WXT    272
#define OFF_WQT    (OFF_WXT + N_MEL*E)        // 20752
#define OFF_WIHT   (OFF_WQT + D_TXT*E)        // 151824
#define OFF_BSUM   (OFF_WIHT + 2*2*256*512)   // 676112
#define OFF_X1     (OFF_BSUM + 2048)          // 678160
#define OFF_Q1     (OFF_X1 + B*T_MEL*E)       // 1497360
#define OFF_G      OFF_X1                      // gates overlay x1+q1 (dead by then)
#define OFF_H0     (OFF_Q1 + B*L_TXT*E)       // 1759504
#define OFF_O1     (OFF_H0 + B*L_TXT*E)       // 2021648
#define OFF_O2     (OFF_O1 + B*L_TXT*HID)     // 2283792

__device__ __forceinline__ float fast_sigmoid(float x){ return 1.f/(1.f+__expf(-x)); }
__device__ __forceinline__ float fast_tanh(float x){ float e=__expf(2.f*x); return 1.f - 2.f/(e+1.f); }

// ---- prep: w = Wout^T v, c = bout.v ; transposes WxT, WqT, WihT ; bias sums ----
__global__ void k_prep(const float* __restrict__ Wout, const float* __restrict__ bout,
                       const float* __restrict__ v,    const float* __restrict__ Wx,
                       const float* __restrict__ Wq,   const float* __restrict__ wih,
                       const float* __restrict__ bih,  const float* __restrict__ bhh,
                       float* __restrict__ ws){
  int blk = blockIdx.x, tid = threadIdx.x;
  if (blk == 0){
    float acc = 0.f;
    for (int j=0;j<E;j++) acc += Wout[j*E + tid] * v[j];
    ws[OFF_W + tid] = acc;
    if (tid==0){ float c=0.f; for(int j=0;j<E;j++) c += bout[j]*v[j]; ws[OFF_C]=c; }
  } else if (blk <= N_MEL){
    int m = blk-1;
    ws[OFF_WXT + m*E + tid] = Wx[tid*N_MEL + m];
  } else if (blk <= N_MEL + D_TXT){
    int k = blk-1-N_MEL;
    ws[OFF_WQT + k*E + tid] = Wq[tid*D_TXT + k];
  } else if (blk <= N_MEL + D_TXT + 1024){
    int idx = blk-1-N_MEL-D_TXT;      // ld*256 + k
    int ld = idx >> 8, k = idx & 255;
    for (int g = tid; g < 512; g += 256)
      ws[OFF_WIHT + idx*512 + g] = wih[(ld*512+g)*256 + k];
  } else {
    for (int i = tid; i < 2048; i += 256)
      ws[OFF_BSUM + i] = bih[i] + bhh[i];
  }
}

// ---- x1[b,t,e] = sum_m x[b,m,t]*Wx[e,m] + bx[e] ; t-tile 4 ----
__global__ __launch_bounds__(256) void k_x1(const float* __restrict__ x,
                                            const float* __restrict__ bx,
                                            float* __restrict__ ws){
  int blk = blockIdx.x; int b = blk/100; int t0 = (blk%100)*4; int tid = threadIdx.x;
  __shared__ float sx[N_MEL][4];
  for (int i = tid; i < N_MEL*4; i += 256){
    int m = i>>2, ii = i&3;
    sx[m][ii] = x[(b*N_MEL+m)*T_MEL + t0 + ii];
  }
  __syncthreads();
  float bxe = bx[tid];
  float a0=bxe,a1=bxe,a2=bxe,a3=bxe;
  const float* wxt = ws + OFF_WXT;
  #pragma unroll 4
  for (int m=0;m<N_MEL;m++){
    float w = wxt[m*E + tid];
    a0 += sx[m][0]*w; a1 += sx[m][1]*w; a2 += sx[m][2]*w; a3 += sx[m][3]*w;
  }
  float* x1 = ws + OFF_X1 + (b*T_MEL + t0)*E + tid;
  x1[0]=a0; x1[E]=a1; x1[2*E]=a2; x1[3*E]=a3;
}

// ---- q1[b,l,e] = sum_d text[b,l,d]*Wq[e,d] + bq[e] ; l-tile 4 ----
__global__ __launch_bounds__(256) void k_q1(const float* __restrict__ text,
                                            const float* __restrict__ bq,
                                            float* __restrict__ ws){
  int blk = blockIdx.x; int b = blk/32; int l0 = (blk%32)*4; int tid = threadIdx.x;
  __shared__ float st[4][D_TXT];
  for (int i = tid; i < 4*D_TXT; i += 256){
    int li = i / D_TXT, k = i % D_TXT;
    st[li][k] = text[(b*L_TXT + l0 + li)*D_TXT + k];
  }
  __syncthreads();
  float bqe = bq[tid];
  float a0=bqe,a1=bqe,a2=bqe,a3=bqe;
  const float* wqt = ws + OFF_WQT;
  #pragma unroll 2
  for (int k=0;k<D_TXT;k++){
    float w = wqt[k*E + tid];
    a0 += st[0][k]*w; a1 += st[1][k]*w; a2 += st[2][k]*w; a3 += st[3][k]*w;
  }
  float* q1 = ws + OFF_Q1 + (b*L_TXT + l0)*E + tid;
  q1[0]=a0; q1[E]=a1; q1[2*E]=a2; q1[3*E]=a3;
}

// ---- scores + masked softmax + context + h0 ; one block per (b,l) ----
__global__ __launch_bounds__(256) void k_score(const int* __restrict__ mel_len,
                                               float* __restrict__ ws,
                                               float* __restrict__ d_out){
  int blk = blockIdx.x; int b = blk >> 7; int l = blk & 127;
  int tid = threadIdx.x; int lane = tid & 63; int wv = tid >> 6;
  __shared__ float sl[T_MEL];
  __shared__ float red[8];
  const float* x1 = ws + OFF_X1 + b*T_MEL*E;
  const float* q1 = ws + OFF_Q1 + (b*L_TXT+l)*E;
  float qv[4], wv4[4];
  #pragma unroll
  for (int j=0;j<4;j++){ qv[j] = q1[lane+64*j]; wv4[j] = ws[OFF_W + lane + 64*j]; }
  float cc = ws[OFF_C];
  int len = mel_len[b];
  for (int t = wv; t < T_MEL; t += 4){
    const float* xr = x1 + t*E;
    float s = 0.f;
    #pragma unroll
    for (int j=0;j<4;j++) s += wv4[j]*fast_tanh(xr[lane+64*j] + qv[j]);
    #pragma unroll
    for (int off=32; off>=1; off>>=1) s += __shfl_xor(s, off);
    if (lane==0) sl[t] = s + cc;
  }
  __syncthreads();
  float mx = -3.0e38f;
  for (int t = tid; t < T_MEL; t += 256) if (t < len) mx = fmaxf(mx, sl[t]);
  #pragma unroll
  for (int off=32; off>=1; off>>=1) mx = fmaxf(mx, __shfl_xor(mx, off));
  if (lane==0) red[wv] = mx;
  __syncthreads();
  mx = fmaxf(fmaxf(red[0],red[1]),fmaxf(red[2],red[3]));
  float se = 0.f;
  for (int t = tid; t < T_MEL; t += 256){
    float p = (t < len) ? __expf(sl[t]-mx) : 0.f;
    sl[t] = p; se += p;
  }
  #pragma unroll
  for (int off=32; off>=1; off>>=1) se += __shfl_xor(se, off);
  if (lane==0) red[4+wv] = se;
  __syncthreads();
  float rsum = 1.f/(red[4]+red[5]+red[6]+red[7]);
  float* sc_out = d_out + 1824 + (b*L_TXT + l)*T_MEL;
  for (int t = tid; t < T_MEL; t += 256){
    float p = sl[t]*rsum;
    sl[t] = p; sc_out[t] = p;
  }
  __syncthreads();
  float a = 0.f;
  int e = tid;
  #pragma unroll 4
  for (int t = 0; t < len; t++) a += sl[t]*x1[t*E + e];
  ws[OFF_H0 + (b*L_TXT+l)*E + e] = q1[e] + a;
}

// ---- gates_in[b,dir,t,g] = gathered_in[b,row(t),:] @ WihT + (bih+bhh) ; t-tile 8 ----
__global__ __launch_bounds__(512) void k_gates(const float* __restrict__ in,
                                               const int* __restrict__ txt_len,
                                               float* __restrict__ gates, int layer,
                                               float* __restrict__ ws){
  int idx = blockIdx.x; int tt = idx & 15; int dir = (idx>>4)&1; int b = idx>>5;
  int tid = threadIdx.x;
  __shared__ float si[8][HID];
  int len = txt_len[b];
  for (int i = tid; i < 8*HID; i += 512){
    int r = i >> 8, k = i & 255;
    int t = tt*8 + r;
    int row = dir ? max(0, len-1-t) : t;
    si[r][k] = in[(b*L_TXT + row)*HID + k];
  }
  __syncthreads();
  int ld = layer*2 + dir;
  int g = tid;
  float bsum = ws[OFF_BSUM + ld*512 + g];
  float acc[8];
  #pragma unroll
  for (int r=0;r<8;r++) acc[r] = bsum;
  const float* wt = ws + OFF_WIHT + ld*256*512;
  for (int k=0;k<HID;k++){
    float w = wt[k*512 + g];
    #pragma unroll
    for (int r=0;r<8;r++) acc[r] += si[r][k]*w;
  }
  float* go = gates + ((b*2+dir)*L_TXT + tt*8)*512 + g;
  #pragma unroll
  for (int r=0;r<8;r++) go[r*512] = acc[r];
}

// ---- recurrent scan v2 ; one block per (b,dir) ; 256 thr; pair (2p,2p+1) owns unit p
//      thread reads only its h-half (64 floats) -> 64KB/step LDS broadcast (was 256KB)
//      one barrier/step via h_hist rolling buffer; out written once at the end ----
__global__ __launch_bounds__(256) void k_scan(const float* __restrict__ gates,
                                              const float* __restrict__ whh_all,
                                              const int* __restrict__ txt_len,
                                              float* __restrict__ out, int layer){
  int dir = blockIdx.x & 1; int b = blockIdx.x >> 1;
  int tid = threadIdx.x;
  int p = tid >> 1;          // hidden unit 0..127
  int q = tid & 1;           // which half of h this thread reads
  __shared__ __align__(16) float h_hist[L_TXT+1][HH];   // row s = h after step s-1 (row 0 = zeros)

  // preload Whh rows {p, p+128, p+256, p+384}, cols [64q, 64q+64) into VGPRs
  const float* wbase = whh_all + (size_t)(layer*2+dir)*512*HH + 64*q;
  float4 w0[16], w1[16], w2[16], w3[16];
  #pragma unroll
  for (int j=0;j<16;j++) w0[j] = ((const float4*)(wbase + (p      )*HH))[j];
  #pragma unroll
  for (int j=0;j<16;j++) w1[j] = ((const float4*)(wbase + (p + 128)*HH))[j];
  #pragma unroll
  for (int j=0;j<16;j++) w2[j] = ((const float4*)(wbase + (p + 256)*HH))[j];
  #pragma unroll
  for (int j=0;j<16;j++) w3[j] = ((const float4*)(wbase + (p + 384)*HH))[j];

  // zero h row 0
  if (tid < HH) h_hist[0][tid] = 0.f;
  int len = txt_len[b];
  const float* gin = gates + (size_t)(b*2+dir)*L_TXT*512;
  float c_reg = 0.f;

  // prefetch step-0 gate inputs: q=0 loads (i,g) rows, q=1 loads (f,o) rows
  float l1 = gin[p + 128*q];
  float l2 = gin[p + 256 + 128*q];
  __syncthreads();

  for (int s=0; s<L_TXT; s++){
    // prefetch next step's gate inputs (latency hidden under this step's FMAs)
    float nl1 = 0.f, nl2 = 0.f;
    if (s+1 < L_TXT){
      nl1 = gin[(s+1)*512 + p + 128*q];
      nl2 = gin[(s+1)*512 + p + 256 + 128*q];
    }
    float acc0 = q ? 0.f : l1;   // i
    float acc1 = q ? l1  : 0.f;  // f
    float acc2 = q ? 0.f : l2;   // g
    float acc3 = q ? l2  : 0.f;  // o
    const float4* hp = (const float4*)(&h_hist[s][64*q]);
    #pragma unroll
    for (int j=0;j<16;j++){
      float4 hv = hp[j];
      acc0 += w0[j].x*hv.x + w0[j].y*hv.y + w0[j].z*hv.z + w0[j].w*hv.w;
      acc1 += w1[j].x*hv.x + w1[j].y*hv.y + w1[j].z*hv.z + w1[j].w*hv.w;
      acc2 += w2[j].x*hv.x + w2[j].y*hv.y + w2[j].z*hv.z + w2[j].w*hv.w;
      acc3 += w3[j].x*hv.x + w3[j].y*hv.y + w3[j].z*hv.z + w3[j].w*hv.w;
    }
    acc0 += __shfl_xor(acc0, 1);
    acc1 += __shfl_xor(acc1, 1);
    acc2 += __shfl_xor(acc2, 1);
    acc3 += __shfl_xor(acc3, 1);
    // both pair-threads now hold full i,f,g,o for unit p (redundant but uniform)
    float ii = fast_sigmoid(acc0);
    float ff = fast_sigmoid(acc1);
    float gg = fast_tanh(acc2);
    float oo = fast_sigmoid(acc3);
    c_reg = ff*c_reg + ii*gg;
    float h = oo*fast_tanh(c_reg);
    if (q==0) h_hist[s+1][p] = h;
    l1 = nl1; l2 = nl2;
    __syncthreads();
  }

  // write outputs once, coalesced; dir=1 applies pack-reverse semantics
  for (int idx = tid; idx < L_TXT*HH; idx += 256){
    int pos = idx >> 7; int u = idx & 127;
    int src = dir ? (pos < len ? len-1-pos : 0) : pos;
    out[(size_t)(b*L_TXT+pos)*HID + dir*HH + u] = h_hist[src+1][u];
  }
}

// ---- masked mean pool + p1/tanh + normalize + p2 ----
__global__ __launch_bounds__(256) void k_final(const float* __restrict__ o2,
                                               const int* __restrict__ txt_len,
                                               const float* __restrict__ p1w,
                                               const float* __restrict__ p1b,
                                               const float* __restrict__ p2w,
                                               const float* __restrict__ p2b,
                                               float* __restrict__ d_out){
  int b = blockIdx.x; int tid = threadIdx.x;
  __shared__ float pl[HID];
  __shared__ float ol[EMB];
  __shared__ float nrm;
  int len = txt_len[b];
  float s = 0.f;
  for (int t=0; t<len; t++) s += o2[(b*L_TXT+t)*HID + tid];
  pl[tid] = s / (float)len;
  __syncthreads();
  if (tid < EMB){
    float a = p1b[tid];
    for (int k=0;k<HID;k++) a += pl[k]*p1w[tid*HID+k];
    ol[tid] = fast_tanh(a);
  }
  __syncthreads();
  if (tid == 0){
    float q = 0.f;
    for (int k=0;k<EMB;k++) q += ol[k]*ol[k];
    nrm = rsqrtf(q);
  }
  __syncthreads();
  if (tid < EMB) d_out[800 + b*EMB + tid] = ol[tid]*nrm;
  if (tid < N_SPK){
    float a = p2b[tid];
    for (int k=0;k<EMB;k++) a += ol[k]*p2w[tid*EMB+k];
    d_out[b*N_SPK + tid] = a;
  }
}

extern "C" void kernel_launch(void* const* d_in, const int* in_sizes, int n_in,
                              void* d_out, int out_size, void* d_ws, size_t ws_size,
                              hipStream_t stream) {
  const float* x       = (const float*)d_in[0];
  const int*   mel_len = (const int*)  d_in[1];
  const float* text    = (const float*)d_in[2];
  const int*   txt_len = (const int*)  d_in[3];
  const float* Wx      = (const float*)d_in[4];
  const float* bx      = (const float*)d_in[5];
  const float* Wq      = (const float*)d_in[6];
  const float* bq      = (const float*)d_in[7];
  const float* Wout    = (const float*)d_in[8];
  const float* bout    = (const float*)d_in[9];
  const float* v       = (const float*)d_in[10];
  const float* wih     = (const float*)d_in[11];
  const float* whh     = (const float*)d_in[12];
  const float* bih     = (const float*)d_in[13];
  const float* bhh     = (const float*)d_in[14];
  const float* p1w     = (const float*)d_in[15];
  const float* p1b     = (const float*)d_in[16];
  const float* p2w     = (const float*)d_in[17];
  const float* p2b     = (const float*)d_in[18];
  float* ws  = (float*)d_ws;
  float* out = (float*)d_out;

  k_prep<<<1618, 256, 0, stream>>>(Wout, bout, v, Wx, Wq, wih, bih, bhh, ws);
  k_x1  <<<800, 256, 0, stream>>>(x, bx, ws);
  k_q1  <<<256, 256, 0, stream>>>(text, bq, ws);
  k_score<<<1024, 256, 0, stream>>>(mel_len, ws, out);

  float* G = ws + OFF_G;
  k_gates<<<256, 512, 0, stream>>>(ws + OFF_H0, txt_len, G, 0, ws);
  k_scan <<<16, 256, 0, stream>>>(G, whh, txt_len, ws + OFF_O1, 0);
  k_gates<<<256, 512, 0, stream>>>(ws + OFF_O1, txt_len, G, 1, ws);
  k_scan <<<16, 256, 0, stream>>>(G, whh, txt_len, ws + OFF_O2, 1);

  k_final<<<8, 256, 0, stream>>>(ws + OFF_O2, txt_len, p1w, p1b, p2w, p2b, out);
}

// Round 3
// 541.502 us; speedup vs baseline: 1.1707x; 1.1471x over previous
//
#include <hip/hip_runtime.h>
#include <hip/hip_bf16.h>
#include <math.h>

#define B 8
#define T_MEL 400
#define N_MEL 80
#define L_TXT 128
#define D_TXT 512
#define E 256
#define HID 256
#define EMB 128
#define N_SPK 100
#define HH 128

// ---- workspace layout (float element offsets) ----
#define OFF_W      0
#define OFF_C      256
#define OFF_WXT    272
#define OFF_WQT    (OFF_WXT + N_MEL*E)        // 20752
#define OFF_WIHT   (OFF_WQT + D_TXT*E)        // 151824
#define OFF_BSUM   (OFF_WIHT + 2*2*256*512)   // 676112
#define OFF_X1     (OFF_BSUM + 2048)          // 678160
#define OFF_Q1     (OFF_X1 + B*T_MEL*E)       // 1497360
#define OFF_G      OFF_X1                      // gates overlay x1+q1 (dead by then)
#define OFF_H0     (OFF_Q1 + B*L_TXT*E)       // 1759504
#define OFF_O1     (OFF_H0 + B*L_TXT*E)       // 2021648
#define OFF_O2     (OFF_O1 + B*L_TXT*HID)     // 2283792

__device__ __forceinline__ float fast_sigmoid(float x){ return 1.f/(1.f+__expf(-x)); }
__device__ __forceinline__ float fast_tanh(float x){ float e=__expf(2.f*x); return 1.f - 2.f/(e+1.f); }

// ---- prep: w = Wout^T v, c = bout.v ; transposes WxT, WqT, WihT ; bias sums ----
__global__ void k_prep(const float* __restrict__ Wout, const float* __restrict__ bout,
                       const float* __restrict__ v,    const float* __restrict__ Wx,
                       const float* __restrict__ Wq,   const float* __restrict__ wih,
                       const float* __restrict__ bih,  const float* __restrict__ bhh,
                       float* __restrict__ ws){
  int blk = blockIdx.x, tid = threadIdx.x;
  if (blk == 0){
    float acc = 0.f;
    for (int j=0;j<E;j++) acc += Wout[j*E + tid] * v[j];
    ws[OFF_W + tid] = acc;
    if (tid==0){ float c=0.f; for(int j=0;j<E;j++) c += bout[j]*v[j]; ws[OFF_C]=c; }
  } else if (blk <= N_MEL){
    int m = blk-1;
    ws[OFF_WXT + m*E + tid] = Wx[tid*N_MEL + m];
  } else if (blk <= N_MEL + D_TXT){
    int k = blk-1-N_MEL;
    ws[OFF_WQT + k*E + tid] = Wq[tid*D_TXT + k];
  } else if (blk <= N_MEL + D_TXT + 1024){
    int idx = blk-1-N_MEL-D_TXT;      // ld*256 + k
    int ld = idx >> 8, k = idx & 255;
    for (int g = tid; g < 512; g += 256)
      ws[OFF_WIHT + idx*512 + g] = wih[(ld*512+g)*256 + k];
  } else {
    for (int i = tid; i < 2048; i += 256)
      ws[OFF_BSUM + i] = bih[i] + bhh[i];
  }
}

// ---- x1[b,t,e] = sum_m x[b,m,t]*Wx[e,m] + bx[e] ; t-tile 4 ----
__global__ __launch_bounds__(256) void k_x1(const float* __restrict__ x,
                                            const float* __restrict__ bx,
                                            float* __restrict__ ws){
  int blk = blockIdx.x; int b = blk/100; int t0 = (blk%100)*4; int tid = threadIdx.x;
  __shared__ float sx[N_MEL][4];
  for (int i = tid; i < N_MEL*4; i += 256){
    int m = i>>2, ii = i&3;
    sx[m][ii] = x[(b*N_MEL+m)*T_MEL + t0 + ii];
  }
  __syncthreads();
  float bxe = bx[tid];
  float a0=bxe,a1=bxe,a2=bxe,a3=bxe;
  const float* wxt = ws + OFF_WXT;
  #pragma unroll 4
  for (int m=0;m<N_MEL;m++){
    float w = wxt[m*E + tid];
    a0 += sx[m][0]*w; a1 += sx[m][1]*w; a2 += sx[m][2]*w; a3 += sx[m][3]*w;
  }
  float* x1 = ws + OFF_X1 + (b*T_MEL + t0)*E + tid;
  x1[0]=a0; x1[E]=a1; x1[2*E]=a2; x1[3*E]=a3;
}

// ---- q1[b,l,e] = sum_d text[b,l,d]*Wq[e,d] + bq[e] ; l-tile 4 ----
__global__ __launch_bounds__(256) void k_q1(const float* __restrict__ text,
                                            const float* __restrict__ bq,
                                            float* __restrict__ ws){
  int blk = blockIdx.x; int b = blk/32; int l0 = (blk%32)*4; int tid = threadIdx.x;
  __shared__ float st[4][D_TXT];
  for (int i = tid; i < 4*D_TXT; i += 256){
    int li = i / D_TXT, k = i % D_TXT;
    st[li][k] = text[(b*L_TXT + l0 + li)*D_TXT + k];
  }
  __syncthreads();
  float bqe = bq[tid];
  float a0=bqe,a1=bqe,a2=bqe,a3=bqe;
  const float* wqt = ws + OFF_WQT;
  #pragma unroll 2
  for (int k=0;k<D_TXT;k++){
    float w = wqt[k*E + tid];
    a0 += st[0][k]*w; a1 += st[1][k]*w; a2 += st[2][k]*w; a3 += st[3][k]*w;
  }
  float* q1 = ws + OFF_Q1 + (b*L_TXT + l0)*E + tid;
  q1[0]=a0; q1[E]=a1; q1[2*E]=a2; q1[3*E]=a3;
}

// ---- scores + masked softmax + context + h0 ; one block per (b,l) ----
__global__ __launch_bounds__(256) void k_score(const int* __restrict__ mel_len,
                                               float* __restrict__ ws,
                                               float* __restrict__ d_out){
  int blk = blockIdx.x; int b = blk >> 7; int l = blk & 127;
  int tid = threadIdx.x; int lane = tid & 63; int wv = tid >> 6;
  __shared__ float sl[T_MEL];
  __shared__ float red[8];
  const float* x1 = ws + OFF_X1 + b*T_MEL*E;
  const float* q1 = ws + OFF_Q1 + (b*L_TXT+l)*E;
  float qv[4], wv4[4];
  #pragma unroll
  for (int j=0;j<4;j++){ qv[j] = q1[lane+64*j]; wv4[j] = ws[OFF_W + lane + 64*j]; }
  float cc = ws[OFF_C];
  int len = mel_len[b];
  for (int t = wv; t < T_MEL; t += 4){
    const float* xr = x1 + t*E;
    float s = 0.f;
    #pragma unroll
    for (int j=0;j<4;j++) s += wv4[j]*fast_tanh(xr[lane+64*j] + qv[j]);
    #pragma unroll
    for (int off=32; off>=1; off>>=1) s += __shfl_xor(s, off);
    if (lane==0) sl[t] = s + cc;
  }
  __syncthreads();
  float mx = -3.0e38f;
  for (int t = tid; t < T_MEL; t += 256) if (t < len) mx = fmaxf(mx, sl[t]);
  #pragma unroll
  for (int off=32; off>=1; off>>=1) mx = fmaxf(mx, __shfl_xor(mx, off));
  if (lane==0) red[wv] = mx;
  __syncthreads();
  mx = fmaxf(fmaxf(red[0],red[1]),fmaxf(red[2],red[3]));
  float se = 0.f;
  for (int t = tid; t < T_MEL; t += 256){
    float p = (t < len) ? __expf(sl[t]-mx) : 0.f;
    sl[t] = p; se += p;
  }
  #pragma unroll
  for (int off=32; off>=1; off>>=1) se += __shfl_xor(se, off);
  if (lane==0) red[4+wv] = se;
  __syncthreads();
  float rsum = 1.f/(red[4]+red[5]+red[6]+red[7]);
  float* sc_out = d_out + 1824 + (b*L_TXT + l)*T_MEL;
  for (int t = tid; t < T_MEL; t += 256){
    float p = sl[t]*rsum;
    sl[t] = p; sc_out[t] = p;
  }
  __syncthreads();
  float a = 0.f;
  int e = tid;
  #pragma unroll 4
  for (int t = 0; t < len; t++) a += sl[t]*x1[t*E + e];
  ws[OFF_H0 + (b*L_TXT+l)*E + e] = q1[e] + a;
}

// ---- gates_in[b,dir,t,g] = gathered_in[b,row(t),:] @ WihT + (bih+bhh) ; t-tile 8 ----
__global__ __launch_bounds__(512) void k_gates(const float* __restrict__ in,
                                               const int* __restrict__ txt_len,
                                               float* __restrict__ gates, int layer,
                                               float* __restrict__ ws){
  int idx = blockIdx.x; int tt = idx & 15; int dir = (idx>>4)&1; int b = idx>>5;
  int tid = threadIdx.x;
  __shared__ float si[8][HID];
  int len = txt_len[b];
  for (int i = tid; i < 8*HID; i += 512){
    int r = i >> 8, k = i & 255;
    int t = tt*8 + r;
    int row = dir ? max(0, len-1-t) : t;
    si[r][k] = in[(b*L_TXT + row)*HID + k];
  }
  __syncthreads();
  int ld = layer*2 + dir;
  int g = tid;
  float bsum = ws[OFF_BSUM + ld*512 + g];
  float acc[8];
  #pragma unroll
  for (int r=0;r<8;r++) acc[r] = bsum;
  const float* wt = ws + OFF_WIHT + ld*256*512;
  for (int k=0;k<HID;k++){
    float w = wt[k*512 + g];
    #pragma unroll
    for (int r=0;r<8;r++) acc[r] += si[r][k]*w;
  }
  float* go = gates + ((b*2+dir)*L_TXT + tt*8)*512 + g;
  #pragma unroll
  for (int r=0;r<8;r++) go[r*512] = acc[r];
}

// ---- recurrent scan v3 ; one block per (b,dir) ; 512 thr
//      thread owns TWO gate rows x half-of-h = 128 weight floats (fits VGPR, no spill)
//      shfl_xor(1) joins h-halves; shfl_xor(2) exchanges {f,o}<->{i*g}; 1 barrier/step ----
__global__ __launch_bounds__(512, 1) void k_scan(const float* __restrict__ gates,
                                                 const float* __restrict__ whh_all,
                                                 const int* __restrict__ txt_len,
                                                 float* __restrict__ out, int layer){
  int dir = blockIdx.x & 1; int b = blockIdx.x >> 1;
  int tid = threadIdx.x;
  int p  = tid >> 2;        // hidden unit 0..127
  int r2 = (tid >> 1) & 1;  // 0: rows (i, g) ; 1: rows (f, o)
  int q  = tid & 1;         // which half of h this thread reads
  __shared__ __align__(16) float h_hist[L_TXT+1][HH];   // row s = h after step s-1

  int rowA = p + 128*r2;        // i (r2=0) or f (r2=1)
  int rowB = p + 256 + 128*r2;  // g (r2=0) or o (r2=1)
  const float* base = whh_all + (size_t)(layer*2+dir)*512*HH + 64*q;
  float4 wA[16], wB[16];
  #pragma unroll
  for (int j=0;j<16;j++) wA[j] = ((const float4*)(base + rowA*HH))[j];
  #pragma unroll
  for (int j=0;j<16;j++) wB[j] = ((const float4*)(base + rowB*HH))[j];

  if (tid < HH) h_hist[0][tid] = 0.f;
  int len = txt_len[b];
  const float* gin = gates + (size_t)(b*2+dir)*L_TXT*512;
  float c_reg = 0.f;
  float lA = gin[rowA], lB = gin[rowB];   // step-0 gate inputs (incl. bias)
  __syncthreads();

  for (int s=0; s<L_TXT; s++){
    // prefetch next step's gate inputs; latency hides under this step's FMAs
    float nA = 0.f, nB = 0.f;
    if (s+1 < L_TXT){
      nA = gin[(s+1)*512 + rowA];
      nB = gin[(s+1)*512 + rowB];
    }
    float accA = q ? 0.f : lA;
    float accB = q ? 0.f : lB;
    const float4* hp = (const float4*)(&h_hist[s][64*q]);
    #pragma unroll
    for (int j=0;j<16;j++){
      float4 hv = hp[j];
      accA += wA[j].x*hv.x + wA[j].y*hv.y + wA[j].z*hv.z + wA[j].w*hv.w;
      accB += wB[j].x*hv.x + wB[j].y*hv.y + wB[j].z*hv.z + wB[j].w*hv.w;
    }
    accA += __shfl_xor(accA, 1);   // join h-halves
    accB += __shfl_xor(accB, 1);
    // r2=0: accA=i, accB=g ; r2=1: accA=f, accB=o
    float vA = fast_sigmoid(accA);                      // i or f
    float vB = r2 ? fast_sigmoid(accB) : fast_tanh(accB); // o or g
    float P  = vA * vB;                                 // i*g (only meaningful r2=0)
    float sendA = r2 ? vA : P;
    float sendB = r2 ? vB : P;
    float recvA = __shfl_xor(sendA, 2);  // r2=0 gets f ; r2=1 gets i*g
    float recvB = __shfl_xor(sendB, 2);  // r2=0 gets o ; r2=1 gets i*g
    float f_ = r2 ? vA    : recvA;
    float P_ = r2 ? recvA : P;
    float o_ = r2 ? vB    : recvB;
    c_reg = f_*c_reg + P_;
    float h = o_*fast_tanh(c_reg);
    if ((tid & 3) == 0) h_hist[s+1][p] = h;
    lA = nA; lB = nB;
    __syncthreads();
  }

  // write outputs once, coalesced; dir=1 applies pack-reverse semantics
  for (int idx = tid; idx < L_TXT*HH; idx += 512){
    int pos = idx >> 7; int u = idx & 127;
    int src = dir ? (pos < len ? len-1-pos : 0) : pos;
    out[(size_t)(b*L_TXT+pos)*HID + dir*HH + u] = h_hist[src+1][u];
  }
}

// ---- masked mean pool + p1/tanh + normalize + p2 ----
__global__ __launch_bounds__(256) void k_final(const float* __restrict__ o2,
                                               const int* __restrict__ txt_len,
                                               const float* __restrict__ p1w,
                                               const float* __restrict__ p1b,
                                               const float* __restrict__ p2w,
                                               const float* __restrict__ p2b,
                                               float* __restrict__ d_out){
  int b = blockIdx.x; int tid = threadIdx.x;
  __shared__ float pl[HID];
  __shared__ float ol[EMB];
  __shared__ float nrm;
  int len = txt_len[b];
  float s = 0.f;
  for (int t=0; t<len; t++) s += o2[(b*L_TXT+t)*HID + tid];
  pl[tid] = s / (float)len;
  __syncthreads();
  if (tid < EMB){
    float a = p1b[tid];
    for (int k=0;k<HID;k++) a += pl[k]*p1w[tid*HID+k];
    ol[tid] = fast_tanh(a);
  }
  __syncthreads();
  if (tid == 0){
    float q = 0.f;
    for (int k=0;k<EMB;k++) q += ol[k]*ol[k];
    nrm = rsqrtf(q);
  }
  __syncthreads();
  if (tid < EMB) d_out[800 + b*EMB + tid] = ol[tid]*nrm;
  if (tid < N_SPK){
    float a = p2b[tid];
    for (int k=0;k<EMB;k++) a += ol[k]*p2w[tid*EMB+k];
    d_out[b*N_SPK + tid] = a;
  }
}

extern "C" void kernel_launch(void* const* d_in, const int* in_sizes, int n_in,
                              void* d_out, int out_size, void* d_ws, size_t ws_size,
                              hipStream_t stream) {
  const float* x       = (const float*)d_in[0];
  const int*   mel_len = (const int*)  d_in[1];
  const float* text    = (const float*)d_in[2];
  const int*   txt_len = (const int*)  d_in[3];
  const float* Wx      = (const float*)d_in[4];
  const float* bx      = (const float*)d_in[5];
  const float* Wq      = (const float*)d_in[6];
  const float* bq      = (const float*)d_in[7];
  const float* Wout    = (const float*)d_in[8];
  const float* bout    = (const float*)d_in[9];
  const float* v       = (const float*)d_in[10];
  const float* wih     = (const float*)d_in[11];
  const float* whh     = (const float*)d_in[12];
  const float* bih     = (const float*)d_in[13];
  const float* bhh     = (const float*)d_in[14];
  const float* p1w     = (const float*)d_in[15];
  const float* p1b     = (const float*)d_in[16];
  const float* p2w     = (const float*)d_in[17];
  const float* p2b     = (const float*)d_in[18];
  float* ws  = (float*)d_ws;
  float* out = (float*)d_out;

  k_prep<<<1618, 256, 0, stream>>>(Wout, bout, v, Wx, Wq, wih, bih, bhh, ws);
  k_x1  <<<800, 256, 0, stream>>>(x, bx, ws);
  k_q1  <<<256, 256, 0, stream>>>(text, bq, ws);
  k_score<<<1024, 256, 0, stream>>>(mel_len, ws, out);

  float* G = ws + OFF_G;
  k_gates<<<256, 512, 0, stream>>>(ws + OFF_H0, txt_len, G, 0, ws);
  k_scan <<<16, 512, 0, stream>>>(G, whh, txt_len, ws + OFF_O1, 0);
  k_gates<<<256, 512, 0, stream>>>(ws + OFF_O1, txt_len, G, 1, ws);
  k_scan <<<16, 512, 0, stream>>>(G, whh, txt_len, ws + OFF_O2, 1);

  k_final<<<8, 256, 0, stream>>>(ws + OFF_O2, txt_len, p1w, p1b, p2w, p2b, out);
}